// Round 6
// baseline (399.687 us; speedup 1.0000x reference)
//
#include <hip/hip_runtime.h>

// out[n,o,j,i] = sum_{a,b} inp[n,2,i+a,j+b] * kt[o,a,b]
//   inp: (32,3,224,224) f32, kt: (64,5,5) f32, out: (32,64,220,220) f32
//
// R5: R4 (OG=8 + nt stores) = 85.8us. Write floor 57.5us. Test the
// overlap/amortization hypothesis for the residual:
//   - OG 8->16: staging redundancy halves (0.135 staged words/output)
//   - launch_bounds(256,8): 8 blocks/CU co-resident (VGPR 32, LDS 9.2KB
//     both allow it) -> more independent blocks to hide stage+sync latency.

#define IMG    224
#define OHW    220
#define FLAT   (OHW * OHW)     // 48400
#define NOUT   64
#define KW     5
#define BLOCK  256
#define QPB    (BLOCK * 4)     // outputs per (block, channel) = 1024
#define NBX    48              // ceil(48400 / 1024)
#define OG     16              // channels per block
#define COLS   10              // staged input columns (<=6 output cols + 4 halo)
#define PR     228             // transposed slab pitch (words), %4==0 for b128
#define SLAB   (COLS * PR)     // 2280 floats = 9120 B

typedef float floatx4 __attribute__((ext_vector_type(4)));

__global__ __launch_bounds__(BLOCK, 8)
void ConvolutionalLayer_88742614270062_kernel(const float* __restrict__ inp,
                                              const float* __restrict__ kt,
                                              float* __restrict__ out) {
    __shared__ float s[SLAB];   // s[c*PR + r]: transposed slab

    const int n   = blockIdx.z;
    const int og  = blockIdx.y * OG;        // first channel of this block
    const int f0  = blockIdx.x * QPB;       // first flat output index
    const int jlo = f0 / OHW;               // first output column touched

    const float* __restrict__ xb = inp + ((size_t)(n * 3 + 2)) * (IMG * IMG);

    // Stage once per block: 224 rows x 10 cols, transposed, right edge guarded.
    for (int idx = threadIdx.x; idx < IMG * COLS; idx += BLOCK) {
        int r   = idx / COLS;
        int c   = idx - r * COLS;
        int col = jlo + c;
        s[c * PR + r] = (col < IMG) ? xb[r * IMG + col] : 0.0f;
    }
    __syncthreads();

    const int  f    = f0 + (int)threadIdx.x * 4;
    const bool live = (f < FLAT);
    const int  fc   = live ? f : (FLAT - 4);    // clamp for safe LDS reads
    const int  j    = fc / OHW;
    const int  i4   = fc - j * OHW;             // multiple of 4
    const int  cj   = j - jlo;                  // 0..5

    // 5 cols x 8 rows window: two aligned conflict-free ds_read_b128 per col.
    float w8[KW][8];
#pragma unroll
    for (int b = 0; b < KW; ++b) {
        const floatx4* p = reinterpret_cast<const floatx4*>(&s[(cj + b) * PR + i4]);
        floatx4 lo = p[0];
        floatx4 hi = p[1];
        w8[b][0] = lo.x; w8[b][1] = lo.y; w8[b][2] = lo.z; w8[b][3] = lo.w;
        w8[b][4] = hi.x; w8[b][5] = hi.y; w8[b][6] = hi.z; w8[b][7] = hi.w;
    }

    // Weights: og wave-uniform -> scalar loads from kt.
    const float* __restrict__ wk = kt + og * (KW * KW);
    float* __restrict__ op = out + ((size_t)(n * NOUT + og)) * FLAT + f;

#pragma unroll
    for (int oc = 0; oc < OG; ++oc) {
        float a0 = 0.f, a1 = 0.f, a2 = 0.f, a3 = 0.f;
#pragma unroll
        for (int a = 0; a < KW; ++a) {
#pragma unroll
            for (int b = 0; b < KW; ++b) {
                float w = wk[oc * (KW * KW) + a * KW + b];
                a0 = fmaf(w, w8[b][a    ], a0);
                a1 = fmaf(w, w8[b][a + 1], a1);
                a2 = fmaf(w, w8[b][a + 2], a2);
                a3 = fmaf(w, w8[b][a + 3], a3);
            }
        }
        if (live) {
            floatx4 v = { a0, a1, a2, a3 };
            __builtin_nontemporal_store(v,
                reinterpret_cast<floatx4*>(op + (size_t)oc * FLAT));
        }
    }
}

extern "C" void kernel_launch(void* const* d_in, const int* in_sizes, int n_in,
                              void* d_out, int out_size, void* d_ws, size_t ws_size,
                              hipStream_t stream) {
    const float* inp = (const float*)d_in[0];   // (32,3,224,224)
    const float* kt  = (const float*)d_in[1];   // (64,5,5)
    float* out       = (float*)d_out;           // (32,64,220,220)

    dim3 grid(NBX, NOUT / OG, 32);              // 48 x 4 x 32 blocks
    ConvolutionalLayer_88742614270062_kernel<<<grid, BLOCK, 0, stream>>>(inp, kt, out);
}

// Round 7
// 193.711 us; speedup vs baseline: 2.0633x; 2.0633x over previous
//
#include <hip/hip_runtime.h>

// out[n,o,j,i] = sum_{a,b} inp[n,2,i+a,j+b] * kt[o,a,b]
//   inp: (32,3,224,224) f32, kt: (64,5,5) f32, out: (32,64,220,220) f32
//
// R6: one write stream per block. Block = (f-chunk, o, n); covers 8192
// consecutive outputs of ONE (n,o) plane via 8 iterations of 4KB
// block-contiguous nt stores -> ~1024 long monotone streams device-wide
// (R4 had ~12K short ones; R5's 32K caused RMW blowup, fetch~=write~=2x).
// Staging amortized over the wide f-span: 43 cols x 224 rows transposed
// slab (39.2KB LDS, exactly 4 blocks/CU), staged once per block.

#define IMG    224
#define OHW    220
#define FLAT   (OHW * OHW)     // 48400
#define NOUT   64
#define KW     5
#define BLOCK  256
#define QPT    8               // quads per thread
#define OPB    (BLOCK * 4 * QPT)  // 8192 outputs per block
#define NBX    6               // ceil(48400 / 8192)
#define COLS   43              // staged input columns (38 output cols + 4 halo, +1)
#define PR     228             // transposed slab pitch (words), %4==0 for b128
#define SLAB   (COLS * PR)     // 9804 words = 39,216 B

typedef float floatx4 __attribute__((ext_vector_type(4)));

__global__ __launch_bounds__(BLOCK, 4)
void ConvolutionalLayer_88742614270062_kernel(const float* __restrict__ inp,
                                              const float* __restrict__ kt,
                                              float* __restrict__ out) {
    __shared__ float s[SLAB];   // s[c*PR + r]: transposed slab

    const int n   = blockIdx.z;
    const int o   = blockIdx.y;
    const int f0  = blockIdx.x * OPB;       // first flat output index
    const int jlo = f0 / OHW;               // first output column touched

    const float* __restrict__ xb = inp + ((size_t)(n * 3 + 2)) * (IMG * IMG);

    // Stage once: 224 rows x 43 cols, transposed, right edge guarded.
    // Global reads coalesced (consecutive idx -> consecutive col);
    // ds_writes 8-way conflicted (stride 228 words) -- accepted, ~14% issue.
    for (int idx = threadIdx.x; idx < IMG * COLS; idx += BLOCK) {
        int r   = idx / COLS;
        int c   = idx - r * COLS;
        int col = jlo + c;
        s[c * PR + r] = (col < IMG) ? xb[r * IMG + col] : 0.0f;
    }
    __syncthreads();

    // Weights: o = blockIdx.y -> wave-uniform -> 25 scalar loads, reused x8.
    const float* __restrict__ wk = kt + o * (KW * KW);
    float w[KW * KW];
#pragma unroll
    for (int t = 0; t < KW * KW; ++t) w[t] = wk[t];

    float* __restrict__ plane = out + ((size_t)(n * NOUT + o)) * FLAT;

#pragma unroll 2
    for (int it = 0; it < QPT; ++it) {
        const int  f    = f0 + (it << 10) + ((int)threadIdx.x << 2);
        const bool live = (f < FLAT);
        const int  fc   = live ? f : (FLAT - 4);   // clamp for safe LDS reads
        const int  j    = fc / OHW;
        const int  i4   = fc - j * OHW;            // multiple of 4
        const int  cj   = j - jlo;                 // 0..38

        // 5 cols x 8 rows window: two aligned conflict-free ds_read_b128/col.
        float w8[KW][8];
#pragma unroll
        for (int b = 0; b < KW; ++b) {
            const floatx4* p =
                reinterpret_cast<const floatx4*>(&s[(cj + b) * PR + i4]);
            floatx4 lo = p[0];
            floatx4 hi = p[1];
            w8[b][0] = lo.x; w8[b][1] = lo.y; w8[b][2] = lo.z; w8[b][3] = lo.w;
            w8[b][4] = hi.x; w8[b][5] = hi.y; w8[b][6] = hi.z; w8[b][7] = hi.w;
        }

        float a0 = 0.f, a1 = 0.f, a2 = 0.f, a3 = 0.f;
#pragma unroll
        for (int a = 0; a < KW; ++a) {
#pragma unroll
            for (int b = 0; b < KW; ++b) {
                float ww = w[a * KW + b];
                a0 = fmaf(ww, w8[b][a    ], a0);
                a1 = fmaf(ww, w8[b][a + 1], a1);
                a2 = fmaf(ww, w8[b][a + 2], a2);
                a3 = fmaf(ww, w8[b][a + 3], a3);
            }
        }

        if (live) {
            floatx4 v = { a0, a1, a2, a3 };
            __builtin_nontemporal_store(v,
                reinterpret_cast<floatx4*>(plane + f));
        }
    }
}

extern "C" void kernel_launch(void* const* d_in, const int* in_sizes, int n_in,
                              void* d_out, int out_size, void* d_ws, size_t ws_size,
                              hipStream_t stream) {
    const float* inp = (const float*)d_in[0];   // (32,3,224,224)
    const float* kt  = (const float*)d_in[1];   // (64,5,5)
    float* out       = (float*)d_out;           // (32,64,220,220)

    dim3 grid(NBX, NOUT, 32);                   // 6 x 64 x 32 blocks
    ConvolutionalLayer_88742614270062_kernel<<<grid, BLOCK, 0, stream>>>(inp, kt, out);
}

// Round 8
// 158.210 us; speedup vs baseline: 2.5263x; 1.2244x over previous
//
#include <hip/hip_runtime.h>

// out[n,o,j,i] = sum_{a,b} inp[n,2,i+a,j+b] * kt[o,a,b]
//   inp: (32,3,224,224) f32, kt: (64,5,5) f32, out: (32,64,220,220) f32
//
// R7: write-span theory. Grid = (fc, o-pair, n) with fc fastest -> the
// ~2048 resident blocks cover CONSECUTIVE o-planes of one image: the
// device-wide store front is one contiguous monotone ~8-16MB window
// (fill-kernel-like, 6.9 TB/s) instead of R4's 170 scattered plane
// streams (4.6 TB/s). OG=2 keeps staging cost ~54 inst/thread; the
// (n,fc) slab is re-staged per o-pair but stays L2-resident.
// LDS: contiguous ds_read_b128 (PR=228) + XOR swizzle on row bits[4:2]
// to make the transposed staging writes ~conflict-free.

#define IMG    224
#define OHW    220
#define FLAT   (OHW * OHW)     // 48400
#define NOUT   64
#define KW     5
#define BLOCK  256
#define QPB    (BLOCK * 4)     // outputs per (block, channel) = 1024
#define NBX    48              // ceil(48400 / 1024)
#define OG     2               // channels per block
#define COLS   10              // staged input columns (6 output cols + 4 halo)
#define PR     228             // slab pitch (words), %4==0 -> aligned b128
#define SLAB   (COLS * PR)     // 2280 words = 9120 B

typedef float floatx4 __attribute__((ext_vector_type(4)));

// swizzled word address of (column c, row r):  XOR row bits[4:2] with c&7
__device__ __forceinline__ int sw(int c, int r) {
    return c * PR + (r ^ ((c & 7) << 2));
}

__global__ __launch_bounds__(BLOCK, 4)
void ConvolutionalLayer_88742614270062_kernel(const float* __restrict__ inp,
                                              const float* __restrict__ kt,
                                              float* __restrict__ out) {
    __shared__ float s[SLAB];

    const int n   = blockIdx.z;
    const int o0  = blockIdx.y * OG;        // first channel of this block
    const int f0  = blockIdx.x * QPB;       // first flat output index
    const int jlo = f0 / OHW;               // first output column touched

    const float* __restrict__ xb = inp + ((size_t)(n * 3 + 2)) * (IMG * IMG);

    // Stage 224 rows x 10 cols, transposed + row-swizzled, right edge guarded.
    // Global reads: ~10-word row segments (coalesced enough, L2-resident).
    // LDS writes: swizzle spreads the stride-228 pattern to ~2-way (free).
    for (int idx = threadIdx.x; idx < IMG * COLS; idx += BLOCK) {
        int r   = idx / COLS;
        int c   = idx - r * COLS;
        int col = jlo + c;
        s[sw(c, r)] = (col < IMG) ? xb[r * IMG + col] : 0.0f;
    }
    __syncthreads();

    const int  f    = f0 + (int)threadIdx.x * 4;
    const bool live = (f < FLAT);
    const int  fc   = live ? f : (FLAT - 4);    // clamp for safe LDS reads
    const int  j    = fc / OHW;
    const int  i4   = fc - j * OHW;             // multiple of 4
    const int  cj   = j - jlo;                  // 0..5

    // 5 cols x 8 rows window: two aligned ds_read_b128 per column.
    // (i4 and i4+4 are 4-word aligned; XOR on bits[4:2] preserves 16B align.)
    float w8[KW][8];
#pragma unroll
    for (int b = 0; b < KW; ++b) {
        const int c = cj + b;
        floatx4 lo = *reinterpret_cast<const floatx4*>(&s[sw(c, i4)]);
        floatx4 hi = *reinterpret_cast<const floatx4*>(&s[sw(c, i4 + 4)]);
        w8[b][0] = lo.x; w8[b][1] = lo.y; w8[b][2] = lo.z; w8[b][3] = lo.w;
        w8[b][4] = hi.x; w8[b][5] = hi.y; w8[b][6] = hi.z; w8[b][7] = hi.w;
    }

    // Weights: o0 wave-uniform -> scalar loads.
    const float* __restrict__ wk = kt + o0 * (KW * KW);
    float* __restrict__ op = out + ((size_t)(n * NOUT + o0)) * FLAT + f;

#pragma unroll
    for (int oc = 0; oc < OG; ++oc) {
        float a0 = 0.f, a1 = 0.f, a2 = 0.f, a3 = 0.f;
#pragma unroll
        for (int a = 0; a < KW; ++a) {
#pragma unroll
            for (int b = 0; b < KW; ++b) {
                float w = wk[oc * (KW * KW) + a * KW + b];
                a0 = fmaf(w, w8[b][a    ], a0);
                a1 = fmaf(w, w8[b][a + 1], a1);
                a2 = fmaf(w, w8[b][a + 2], a2);
                a3 = fmaf(w, w8[b][a + 3], a3);
            }
        }
        if (live) {
            floatx4 v = { a0, a1, a2, a3 };
            __builtin_nontemporal_store(v,
                reinterpret_cast<floatx4*>(op + (size_t)oc * FLAT));
        }
    }
}

extern "C" void kernel_launch(void* const* d_in, const int* in_sizes, int n_in,
                              void* d_out, int out_size, void* d_ws, size_t ws_size,
                              hipStream_t stream) {
    const float* inp = (const float*)d_in[0];   // (32,3,224,224)
    const float* kt  = (const float*)d_in[1];   // (64,5,5)
    float* out       = (float*)d_out;           // (32,64,220,220)

    // fc fastest, then o-pair, then n: resident blocks sweep consecutive
    // o-planes of one image -> contiguous monotone write front.
    dim3 grid(NBX, NOUT / OG, 32);              // 48 x 32 x 32 blocks
    ConvolutionalLayer_88742614270062_kernel<<<grid, BLOCK, 0, stream>>>(inp, kt, out);
}

// Round 9
// 126.491 us; speedup vs baseline: 3.1598x; 1.2508x over previous
//
#include <hip/hip_runtime.h>

// out[n,o,j,i] = sum_{a,b} inp[n,2,i+a,j+b] * kt[o,a,b]
//   inp: (32,3,224,224) f32, kt: (64,5,5) f32, out: (32,64,220,220) f32
//
// R8: exact A/B against R4 (85.8us, the best so far). Single variable:
// REGULAR stores instead of nontemporal. Rationale: the 6.9 TB/s fill
// kernel uses regular stores; every wave-store here writes 8 complete
// 128B lines, the ideal L2 writeback pattern. nt's evict-first hint may
// be what caps R4 at 4.6 TB/s effective.

#define IMG    224
#define OHW    220
#define FLAT   (OHW * OHW)     // 48400
#define NOUT   64
#define KW     5
#define BLOCK  256
#define QPB    (BLOCK * 4)     // outputs per (block, channel) = 1024
#define NBX    48              // ceil(48400 / 1024)
#define OG     8               // channels per block
#define COLS   10              // staged input columns (<=6 output cols + 4 halo)
#define PR     228             // transposed slab pitch (words), %4==0 for b128
#define SLAB   (COLS * PR)     // 2280 floats = 9120 B

typedef float floatx4 __attribute__((ext_vector_type(4)));

__global__ __launch_bounds__(BLOCK, 4)
void ConvolutionalLayer_88742614270062_kernel(const float* __restrict__ inp,
                                              const float* __restrict__ kt,
                                              float* __restrict__ out) {
    __shared__ float s[SLAB];   // s[c*PR + r]: transposed slab

    const int n   = blockIdx.z;
    const int og  = blockIdx.y * OG;        // first channel of this block
    const int f0  = blockIdx.x * QPB;       // first flat output index
    const int jlo = f0 / OHW;               // first output column touched

    const float* __restrict__ xb = inp + ((size_t)(n * 3 + 2)) * (IMG * IMG);

    // Stage once per block: 224 rows x 10 cols, transposed, right edge guarded.
    for (int idx = threadIdx.x; idx < IMG * COLS; idx += BLOCK) {
        int r   = idx / COLS;
        int c   = idx - r * COLS;
        int col = jlo + c;
        s[c * PR + r] = (col < IMG) ? xb[r * IMG + col] : 0.0f;
    }
    __syncthreads();

    const int  f    = f0 + (int)threadIdx.x * 4;
    const bool live = (f < FLAT);
    const int  fc   = live ? f : (FLAT - 4);    // clamp for safe LDS reads
    const int  j    = fc / OHW;
    const int  i4   = fc - j * OHW;             // multiple of 4
    const int  cj   = j - jlo;                  // 0..5

    // 5 cols x 8 rows window: two aligned conflict-free ds_read_b128 per col.
    float w8[KW][8];
#pragma unroll
    for (int b = 0; b < KW; ++b) {
        const floatx4* p = reinterpret_cast<const floatx4*>(&s[(cj + b) * PR + i4]);
        floatx4 lo = p[0];
        floatx4 hi = p[1];
        w8[b][0] = lo.x; w8[b][1] = lo.y; w8[b][2] = lo.z; w8[b][3] = lo.w;
        w8[b][4] = hi.x; w8[b][5] = hi.y; w8[b][6] = hi.z; w8[b][7] = hi.w;
    }

    // Weights: og wave-uniform -> scalar loads from kt.
    const float* __restrict__ wk = kt + og * (KW * KW);
    float* __restrict__ op = out + ((size_t)(n * NOUT + og)) * FLAT + f;

#pragma unroll
    for (int oc = 0; oc < OG; ++oc) {
        float a0 = 0.f, a1 = 0.f, a2 = 0.f, a3 = 0.f;
#pragma unroll
        for (int a = 0; a < KW; ++a) {
#pragma unroll
            for (int b = 0; b < KW; ++b) {
                float w = wk[oc * (KW * KW) + a * KW + b];
                a0 = fmaf(w, w8[b][a    ], a0);
                a1 = fmaf(w, w8[b][a + 1], a1);
                a2 = fmaf(w, w8[b][a + 2], a2);
                a3 = fmaf(w, w8[b][a + 3], a3);
            }
        }
        if (live) {
            floatx4 v = { a0, a1, a2, a3 };
            *reinterpret_cast<floatx4*>(op + (size_t)oc * FLAT) = v;  // regular store
        }
    }
}

extern "C" void kernel_launch(void* const* d_in, const int* in_sizes, int n_in,
                              void* d_out, int out_size, void* d_ws, size_t ws_size,
                              hipStream_t stream) {
    const float* inp = (const float*)d_in[0];   // (32,3,224,224)
    const float* kt  = (const float*)d_in[1];   // (64,5,5)
    float* out       = (float*)d_out;           // (32,64,220,220)

    dim3 grid(NBX, NOUT / OG, 32);              // 48 x 8 x 32 blocks
    ConvolutionalLayer_88742614270062_kernel<<<grid, BLOCK, 0, stream>>>(inp, kt, out);
}